// Round 2
// baseline (254.751 us; speedup 1.0000x reference)
//
#include <hip/hip_runtime.h>
#include <cstdint>
#include <cstddef>

#define B_ 16
#define Q_ 4096
#define G_ 128
#define C_ 80
#define QCHUNK 16
#define NCH (Q_ / QCHUNK)   // 256 chunks

typedef unsigned long long u64;
#define U64MAX 0xffffffffffffffffull

// pack (cost,q) into a sortable u64 key: asc key order == lex (cost asc, q asc)
__device__ __forceinline__ u64 packkey(float v, int q) {
    unsigned int bts = __float_as_uint(v);
    if (bts == 0x80000000u) bts = 0u;  // -0.0 -> +0.0
    bts = (bts & 0x80000000u) ? ~bts : (bts | 0x80000000u);
    return ((u64)bts << 32) | (unsigned int)q;
}

__device__ __forceinline__ u64 umin64(u64 a, u64 b) { return a < b ? a : b; }
__device__ __forceinline__ u64 umax64(u64 a, u64 b) { return a > b ? a : b; }

// merge two desc-sorted 5-lists -> top-5 desc (branchless network)
__device__ __forceinline__ void merge5_desc(
    float& a0, float& a1, float& a2, float& a3, float& a4,
    float b0, float b1, float b2, float b3, float b4)
{
    const float r0 = fmaxf(a0, b0);
    const float r1 = fmaxf(fmaxf(a1, b1), fminf(a0, b0));
    const float r2 = fmaxf(fmaxf(a2, b2), fmaxf(fminf(a0, b1), fminf(a1, b0)));
    const float r3 = fmaxf(fmaxf(a3, b3),
                     fmaxf(fminf(a0, b2), fmaxf(fminf(a1, b1), fminf(a2, b0))));
    const float r4 = fmaxf(fmaxf(a4, b4),
                     fmaxf(fmaxf(fminf(a0, b3), fminf(a3, b0)),
                           fmaxf(fminf(a1, b2), fminf(a2, b1))));
    a0 = r0; a1 = r1; a2 = r2; a3 = r3; a4 = r4;
}

// merge two asc-sorted 5-lists of u64 keys -> bottom-5 asc
__device__ __forceinline__ void merge5_asc(
    u64& a0, u64& a1, u64& a2, u64& a3, u64& a4,
    u64 b0, u64 b1, u64 b2, u64 b3, u64 b4)
{
    const u64 r0 = umin64(a0, b0);
    const u64 r1 = umin64(umin64(a1, b1), umax64(a0, b0));
    const u64 r2 = umin64(umin64(a2, b2), umin64(umax64(a0, b1), umax64(a1, b0)));
    const u64 r3 = umin64(umin64(a3, b3),
                   umin64(umax64(a0, b2), umin64(umax64(a1, b1), umax64(a2, b0))));
    const u64 r4 = umin64(umin64(a4, b4),
                   umin64(umin64(umax64(a0, b3), umax64(a3, b0)),
                          umin64(umax64(a1, b2), umax64(a2, b1))));
    a0 = r0; a1 = r1; a2 = r2; a3 = r3; a4 = r4;
}

__device__ __forceinline__ float focal_cost(float x) {
    float p;
    if (x >= 0.f) { const float e = expf(-x); p = 1.f / (1.f + e); }
    else          { const float e = expf(x);  p = e / (1.f + e); }
    const float pos = 0.25f * (1.f - p) * (1.f - p) * (-logf(p + 1e-8f));
    const float neg = 0.75f * p * p * (-logf(1.f - p + 1e-8f));
    return pos - neg;
}

// stable conditional-swap insertion level for (cost,q) lex order (strict <)
__device__ __forceinline__ void ins_level(float& c, int& j, float& x, int& qx) {
    const bool s  = x < c;
    const float nc = s ? x : c;
    const float nx = s ? c : x;
    const int   nj = s ? qx : j;
    const int   nq = s ? j : qx;
    c = nc; x = nx; j = nj; qx = nq;
}

// ---------------------------------------------------------------------------
// Kernel A: fused cost/iou + focal (in-LDS); selection + row-argmin in a
// post-pass over a float2 LDS tile (threads 0..127 column lists, 128..255
// row argmin).  Also zeroes cnt.
// ---------------------------------------------------------------------------
__global__ __launch_bounds__(256) void fused_cost_kernel(
    const float* __restrict__ logits,
    const float* __restrict__ pboxes,
    const float* __restrict__ gboxes,
    const int*   __restrict__ glabels,
    float* __restrict__ out_cost,
    float* __restrict__ out_iou,
    float* __restrict__ piou,
    u64*   __restrict__ pcost,
    int*   __restrict__ ramin,
    int*   __restrict__ cnt)
{
    const int tid = threadIdx.x;
    const int g   = tid & 127;
    const int qh  = tid >> 7;
    const int ci  = blockIdx.x, b = blockIdx.y;
    const int q0  = ci * QCHUNK;

    __shared__ float pq[QCHUNK][16];
    __shared__ int   fgf[QCHUNK];
    __shared__ float lbuf[QCHUNK * 80];          // focal class-cost table
    __shared__ float2 citile[QCHUNK][G_ + 2];    // (cost, iou) per pair

    // zero cnt for this block's 16 q's (consumed by dynk after fused completes)
    if (tid < QCHUNK) cnt[b * Q_ + q0 + tid] = 0;

    // ---- per-thread gt constants ----
    const float4* gb4 = (const float4*)(gboxes + ((size_t)b * G_ + g) * 8);
    const float4 gA = gb4[0], gB = gb4[1];
    const float g0 = gA.x, g1 = gA.y, g2 = gA.z, g3 = gA.w;
    const float g4 = gB.x, g5 = gB.y, g6 = gB.z, g7 = gB.w;
    const float gxc = (g0 + g2 + g4 + g6) * 0.25f;
    const float gyc = (g1 + g3 + g5 + g7) * 0.25f;
    const float gw = sqrtf((g0 - g2) * (g0 - g2) + (g1 - g3) * (g1 - g3));
    const float gh = sqrtf((g2 - g4) * (g2 - g4) + (g3 - g5) * (g3 - g5));
    const float gax0 = gxc - gw * 0.5f, gay0 = gyc - gh * 0.5f;
    const float gax1 = gxc + gw * 0.5f, gay1 = gyc + gh * 0.5f;
    const float garea = (gax1 - gax0) * (gay1 - gay0);
    const float v1x = g2 - g0, v1y = g3 - g1, v2x = g4 - g0, v2y = g5 - g1;
    const float gt_area = fabsf(v1x * v2y - v1y * v2x) * 0.5f;
    const float mxx = fmaxf(fmaxf(g0, g2), fmaxf(g4, g6));
    const float mnx = fminf(fminf(g0, g2), fminf(g4, g6));
    const float mxy = fmaxf(fmaxf(g1, g3), fmaxf(g5, g7));
    const float mny = fminf(fminf(g1, g3), fminf(g5, g7));
    const float dgx = mxx - mnx, dgy = mxy - mny;
    const float radius = sqrtf(dgx * dgx + dgy * dgy) / 32.0f;
    const float thresh = gt_area / radius;
    const int lab = glabels[b * G_ + g];

    // ---- stage pred boxes (16 q x 8 floats = 32 float4) ----
    if (tid < 32) {
        const float4 v = ((const float4*)(pboxes + ((size_t)b * Q_ + q0) * 8))[tid];
        *(float4*)&pq[tid >> 1][(tid & 1) * 4] = v;
    }
    __syncthreads();
    if (tid < QCHUNK) {
        const float* pr = pq[tid];
        const float p0 = pr[0], p1 = pr[1], p2 = pr[2], p3 = pr[3];
        const float p4 = pr[4], p5v = pr[5], p6 = pr[6], p7 = pr[7];
        const float pxc = (p0 + p2 + p4 + p6) * 0.25f;
        const float pyc = (p1 + p3 + p5v + p7) * 0.25f;
        const float pw = sqrtf((p0 - p2) * (p0 - p2) + (p1 - p3) * (p1 - p3));
        const float ph = sqrtf((p2 - p4) * (p2 - p4) + (p3 - p5v) * (p3 - p5v));
        pq[tid][8]  = pxc;
        pq[tid][9]  = pyc;
        pq[tid][10] = pxc - pw * 0.5f;
        pq[tid][11] = pyc - ph * 0.5f;
        pq[tid][12] = pxc + pw * 0.5f;
        pq[tid][13] = pyc + ph * 0.5f;
        pq[tid][14] = pw * ph;
        fgf[tid] = 0;
    }
    // focal class-cost table for this chunk (16 q x 80 classes)
    __syncthreads();
    for (int j = tid; j < QCHUNK * 80; j += 256)
        lbuf[j] = focal_cost(logits[((size_t)b * Q_ + q0) * 80 + j]);

    // ---- fg mask (any over g); fgf written by lane0 of each wave ----
    const int lane0 = ((tid & 63) == 0);
    for (int i = 0; i < QCHUNK / 2; ++i) {
        const int ql = 2 * i + qh;
        const float dx = pq[ql][8] - gxc, dy = pq[ql][9] - gyc;
        const int in = sqrtf(dx * dx + dy * dy) <= thresh;
        const int anyin = __any(in);
        if (anyin && lane0) fgf[ql] = 1;
    }
    __syncthreads();

    // ---- main loop: full cost + (cost,iou) tile write; no list upkeep ----
    #pragma unroll
    for (int jj = 0; jj < 8; ++jj) {
        const int qls = 2 * jj + qh;       // 0..15
        const int q   = q0 + qls;
        const float4 prA = *(const float4*)&pq[qls][0];
        const float4 prB = *(const float4*)&pq[qls][4];
        const float4 prC = *(const float4*)&pq[qls][8];
        const float4 prD = *(const float4*)&pq[qls][12];
        const float p0 = prA.x, p1 = prA.y, p2 = prA.z, p3 = prA.w;
        const float p4 = prB.x, p5v = prB.y, p6 = prB.z, p7 = prB.w;
        const float pxc = prC.x, pyc = prC.y;
        const float pax0 = prC.z, pay0 = prC.w, pax1 = prD.x, pay1 = prD.y;
        const float parea = prD.z;

        const float l1 = fabsf(p0 - g0) + fabsf(p1 - g1) + fabsf(p2 - g2)
                       + fabsf(p3 - g3) + fabsf(p4 - g4) + fabsf(p5v - g5)
                       + fabsf(p6 - g6) + fabsf(p7 - g7);

        const float ltx = fmaxf(pax0, gax0), lty = fmaxf(pay0, gay0);
        const float rbx = fminf(pax1, gax1), rby = fminf(pay1, gay1);
        const float iw = fmaxf(rbx - ltx, 0.f), ih = fmaxf(rby - lty, 0.f);
        const float inter = iw * ih;
        const float iou = inter / (parea + garea - inter + 1e-8f);

        const float ew = fmaxf(pax1, gax1) - fminf(pax0, gax0);
        const float eh = fmaxf(pay1, gay1) - fminf(pay0, gay0);
        const float cc2 = ew * ew + eh * eh + 1e-8f;
        const float dx = pxc - gxc, dy = pyc - gyc;
        const float diou = iou - (dx * dx + dy * dy) / cc2;

        const float cclass = lbuf[qls * 80 + lab];
        const float cost = 5.f * l1 + 2.f * cclass + 2.f * diou
                         + (fgf[qls] ? 0.f : 10000.f);

        const size_t o = ((size_t)b * Q_ + q) * G_ + g;
        out_cost[o] = cost;
        out_iou[o]  = iou;
        citile[qls][g] = make_float2(cost, iou);
    }
    __syncthreads();   // citile complete

    if (tid < G_) {
        // ---- per-column selection: bottom-5 (cost,q) lex + top-5 iou ----
        float c0 = 1e38f, c1 = 1e38f, c2 = 1e38f, c3 = 1e38f, c4 = 1e38f;
        int   j0 = 0, j1 = 0, j2 = 0, j3 = 0, j4 = 0;
        float t0 = 0.f, t1 = 0.f, t2 = 0.f, t3 = 0.f, t4 = 0.f;
        #pragma unroll
        for (int q = 0; q < QCHUNK; ++q) {
            const float2 cv = citile[q][tid];
            float x = cv.x; int qx = q;
            ins_level(c0, j0, x, qx);
            ins_level(c1, j1, x, qx);
            ins_level(c2, j2, x, qx);
            ins_level(c3, j3, x, qx);
            ins_level(c4, j4, x, qx);
            float y = cv.y, m;
            m = fmaxf(t0, y); y = fminf(t0, y); t0 = m;
            m = fmaxf(t1, y); y = fminf(t1, y); t1 = m;
            m = fmaxf(t2, y); y = fminf(t2, y); t2 = m;
            m = fmaxf(t3, y); y = fminf(t3, y); t3 = m;
            t4 = fmaxf(t4, y);
        }
        // coalesced layout: [B][NCH][G][5]
        const size_t pbase = (((size_t)b * NCH + ci) * G_ + tid) * 5;
        piou[pbase + 0] = t0; piou[pbase + 1] = t1; piou[pbase + 2] = t2;
        piou[pbase + 3] = t3; piou[pbase + 4] = t4;
        pcost[pbase + 0] = packkey(c0, q0 + j0);
        pcost[pbase + 1] = packkey(c1, q0 + j1);
        pcost[pbase + 2] = packkey(c2, q0 + j2);
        pcost[pbase + 3] = packkey(c3, q0 + j3);
        pcost[pbase + 4] = packkey(c4, q0 + j4);
    } else {
        // ---- row argmin (first-index tie-break), 8 lanes per q ----
        const int t    = tid - 128;
        const int part = t & 7;        // 0..7
        const int row  = t >> 3;       // 0..15
        float v = 1e38f; int mg = 0x7fffffff;
        #pragma unroll
        for (int j = 0; j < 16; ++j) {
            const int gg = part + 8 * j;           // ascending per lane
            const float c = citile[row][gg].x;
            if (c < v) { v = c; mg = gg; }         // strict <: first index
        }
        #pragma unroll
        for (int off = 1; off < 8; off <<= 1) {
            const float ov = __shfl_xor(v, off);
            const int   og = __shfl_xor(mg, off);
            if (ov < v || (ov == v && og < mg)) { v = ov; mg = og; }
        }
        if (part == 0) ramin[b * Q_ + q0 + row] = mg;
    }
}

// ---------------------------------------------------------------------------
// Kernel B: per-column (block=256 = one thread per chunk-list): merge 256
// sorted 5-lists (cost keys asc, iou desc) -> cand, dyn_k, scatter.
// ---------------------------------------------------------------------------
__global__ __launch_bounds__(256) void dynk_scatter_kernel(
    const u64*   __restrict__ pcost,
    const float* __restrict__ piou,
    u64* __restrict__ cand,
    int* __restrict__ cnt,
    int* __restrict__ gsel)
{
    const int col = blockIdx.x;          // b*G + g
    const int b = col >> 7, g = col & 127;
    const int tid = threadIdx.x;         // = chunk index ci
    const int wv = tid >> 6, ln = tid & 63;

    __shared__ u64   wl[4][5];
    __shared__ float il[4][5];

    // layout [B][NCH][G][5]
    const size_t base = (((size_t)b * NCH + tid) * G_ + g) * 5;

    u64 k0 = pcost[base + 0], k1 = pcost[base + 1], k2 = pcost[base + 2],
        k3 = pcost[base + 3], k4 = pcost[base + 4];
    float t0 = piou[base + 0], t1 = piou[base + 1], t2 = piou[base + 2],
          t3 = piou[base + 3], t4 = piou[base + 4];

    #pragma unroll
    for (int off = 1; off < 64; off <<= 1) {
        merge5_asc(k0, k1, k2, k3, k4,
                   __shfl_xor(k0, off), __shfl_xor(k1, off), __shfl_xor(k2, off),
                   __shfl_xor(k3, off), __shfl_xor(k4, off));
        merge5_desc(t0, t1, t2, t3, t4,
                    __shfl_xor(t0, off), __shfl_xor(t1, off), __shfl_xor(t2, off),
                    __shfl_xor(t3, off), __shfl_xor(t4, off));
    }
    if (ln == 0) {
        wl[wv][0] = k0; wl[wv][1] = k1; wl[wv][2] = k2; wl[wv][3] = k3; wl[wv][4] = k4;
        il[wv][0] = t0; il[wv][1] = t1; il[wv][2] = t2; il[wv][3] = t3; il[wv][4] = t4;
    }
    __syncthreads();

    if (tid == 0) {
        u64 f0 = wl[0][0], f1 = wl[0][1], f2 = wl[0][2], f3 = wl[0][3], f4 = wl[0][4];
        merge5_asc(f0, f1, f2, f3, f4, wl[1][0], wl[1][1], wl[1][2], wl[1][3], wl[1][4]);
        merge5_asc(f0, f1, f2, f3, f4, wl[2][0], wl[2][1], wl[2][2], wl[2][3], wl[2][4]);
        merge5_asc(f0, f1, f2, f3, f4, wl[3][0], wl[3][1], wl[3][2], wl[3][3], wl[3][4]);
        float s0 = il[0][0], s1 = il[0][1], s2 = il[0][2], s3 = il[0][3], s4 = il[0][4];
        merge5_desc(s0, s1, s2, s3, s4, il[1][0], il[1][1], il[1][2], il[1][3], il[1][4]);
        merge5_desc(s0, s1, s2, s3, s4, il[2][0], il[2][1], il[2][2], il[2][3], il[2][4]);
        merge5_desc(s0, s1, s2, s3, s4, il[3][0], il[3][1], il[3][2], il[3][3], il[3][4]);

        cand[(size_t)col * 5 + 0] = f0;
        cand[(size_t)col * 5 + 1] = f1;
        cand[(size_t)col * 5 + 2] = f2;
        cand[(size_t)col * 5 + 3] = f3;
        cand[(size_t)col * 5 + 4] = f4;

        const float s = s0 + s1 + s2 + s3 + s4;
        int dynk = (int)s;
        if (dynk < 1) dynk = 1;
        if (dynk > 5) dynk = 5;
        const u64 ks[5] = {f0, f1, f2, f3, f4};
        #pragma unroll
        for (int i = 0; i < 5; ++i) {
            if (i < dynk) {
                const int q = (int)(ks[i] & 0xffffffffu);
                atomicAdd(&cnt[b * Q_ + q], 1);
                gsel[b * Q_ + q] = g;   // only read when cnt==1
            }
        }
    }
}

// ---------------------------------------------------------------------------
// Kernel C: per-batch refinement loop, ONE WAVE per batch (64 threads).
// Workgroup == wavefront so every __syncthreads() is barrier-free (waitcnt
// only) -- the 16-wave version spent ~6 full-block barriers per iteration
// with <=2 waves doing work.  Each lane owns columns g=ln and g=ln+64.
// Algorithm identical: propose first-unmatched candidate from asc (cost,q)
// list; fallback = cooperative strided rescan refilling bottom-5 unmatched;
// dedup: 1 hit -> proposer, >1 hits -> row-argmin column.
// ---------------------------------------------------------------------------
__global__ __launch_bounds__(64) void loop_kernel(
    const float* __restrict__ cost,
    const int* __restrict__ cnt,
    const int* __restrict__ gsel,
    const int* __restrict__ ramin,
    const u64* __restrict__ cand,
    int* __restrict__ rmatch_final)
{
    const int b = blockIdx.x, ln = threadIdx.x;

    __shared__ short rmatch[Q_];            // 8 KB
    __shared__ unsigned char s_ra[Q_];      // 4 KB
    __shared__ int  newh[Q_];               // 16 KB
    __shared__ unsigned char newg[Q_];      // 4 KB
    __shared__ u64 scand[G_][5];            // 5 KB
    __shared__ int ptrs[G_], col_cnt[G_], prop[G_], fb_list[G_];
    __shared__ int n_fb;

    for (int q = ln; q < Q_; q += 64) {
        const int c  = cnt[b * Q_ + q];
        const int ra = ramin[b * Q_ + q];
        s_ra[q] = (unsigned char)ra;
        newh[q] = 0;
        rmatch[q] = (c == 0) ? (short)-1
                             : (c == 1 ? (short)gsel[b * Q_ + q] : (short)ra);
    }
    col_cnt[ln] = 0; col_cnt[ln + 64] = 0;
    ptrs[ln] = 0;    ptrs[ln + 64] = 0;
    for (int i = ln; i < G_ * 5; i += 64)
        scand[i / 5][i % 5] = cand[(size_t)b * G_ * 5 + i];
    __syncthreads();
    for (int q = ln; q < Q_; q += 64)
        if (rmatch[q] >= 0) atomicAdd(&col_cnt[rmatch[q]], 1);
    __syncthreads();

    const float* costb = cost + (size_t)b * Q_ * G_;

    for (int it = 0; it < G_; ++it) {
        if (ln == 0) n_fb = 0;
        __syncthreads();
        const int um0 = (col_cnt[ln] == 0);
        const int um1 = (col_cnt[ln + 64] == 0);
        if (!__any(um0 | um1)) break;

        // propose: first unmatched candidate, else mark for fallback scan
        #pragma unroll
        for (int half = 0; half < 2; ++half) {
            const int um = half ? um1 : um0;
            if (um) {
                const int g = ln + half * 64;
                int p = ptrs[g], q = -1;
                while (p < 5) {
                    const int cq = (int)(scand[g][p] & 0xffffffffu);
                    if (rmatch[cq] < 0) { q = cq; break; }
                    ++p;
                }
                ptrs[g] = p;
                prop[g] = q;
                if (q < 0) fb_list[atomicAdd(&n_fb, 1)] = g;
            }
        }
        __syncthreads();

        // fallback (rare): cooperative bottom-5 of unmatched rows + refill
        const int nf = n_fb;
        for (int i = 0; i < nf; ++i) {
            const int g = fb_list[i];
            const float* colp = costb + g;
            u64 k0 = U64MAX, k1 = U64MAX, k2 = U64MAX, k3 = U64MAX, k4 = U64MAX;
            for (int q = ln; q < Q_; q += 64) {
                if (rmatch[q] < 0) {
                    const u64 kk = packkey(colp[(size_t)q * G_], q);
                    if (kk < k4) {
                        if (kk < k0)      { k4 = k3; k3 = k2; k2 = k1; k1 = k0; k0 = kk; }
                        else if (kk < k1) { k4 = k3; k3 = k2; k2 = k1; k1 = kk; }
                        else if (kk < k2) { k4 = k3; k3 = k2; k2 = kk; }
                        else if (kk < k3) { k4 = k3; k3 = kk; }
                        else              { k4 = kk; }
                    }
                }
            }
            #pragma unroll
            for (int off = 1; off < 64; off <<= 1) {
                merge5_asc(k0, k1, k2, k3, k4,
                           __shfl_xor(k0, off), __shfl_xor(k1, off), __shfl_xor(k2, off),
                           __shfl_xor(k3, off), __shfl_xor(k4, off));
            }
            if (ln == 0) {
                scand[g][0] = k0; scand[g][1] = k1; scand[g][2] = k2;
                scand[g][3] = k3; scand[g][4] = k4;
                ptrs[g] = 0;
                prop[g] = (int)(k0 & 0xffffffffu);
            }
        }
        __syncthreads();

        // hits: count per-row proposals (hits land only on unmatched rows)
        int first0 = 0, first1 = 0;
        if (um0) {
            const int q = prop[ln];
            newg[q] = (unsigned char)ln;
            first0 = (atomicAdd(&newh[q], 1) == 0);
        }
        if (um1) {
            const int q = prop[ln + 64];
            newg[q] = (unsigned char)(ln + 64);
            first1 = (atomicAdd(&newh[q], 1) == 0);
        }
        __syncthreads();

        // resolve (dedup) by first-touchers
        if (first0) {
            const int q = prop[ln];
            const int nh = newh[q];
            const int gg = (nh == 1) ? ln : (int)s_ra[q];
            rmatch[q] = (short)gg;
            atomicAdd(&col_cnt[gg], 1);
            newh[q] = 0;
        }
        if (first1) {
            const int q = prop[ln + 64];
            const int nh = newh[q];
            const int gg = (nh == 1) ? (ln + 64) : (int)s_ra[q];
            rmatch[q] = (short)gg;
            atomicAdd(&col_cnt[gg], 1);
            newh[q] = 0;
        }
        __syncthreads();
    }

    for (int q = ln; q < Q_; q += 64)
        rmatch_final[b * Q_ + q] = rmatch[q];
}

// ---------------------------------------------------------------------------
// Kernel D: expand rmatch -> full match plane (fully parallel float4 writes).
// ---------------------------------------------------------------------------
__global__ __launch_bounds__(256) void expand_kernel(
    const int* __restrict__ rmatch_final, float* __restrict__ out_match)
{
    const int idx = blockIdx.x * 256 + threadIdx.x;  // float4 index
    const int row = idx >> 5;                        // G/4 = 32 float4 per row
    const int gb  = (idx & 31) << 2;
    const int rm  = rmatch_final[row];
    float4 o;
    o.x = (rm == gb)     ? 1.f : 0.f;
    o.y = (rm == gb + 1) ? 1.f : 0.f;
    o.z = (rm == gb + 2) ? 1.f : 0.f;
    o.w = (rm == gb + 3) ? 1.f : 0.f;
    ((float4*)out_match)[idx] = o;
}

extern "C" void kernel_launch(void* const* d_in, const int* in_sizes, int n_in,
                              void* d_out, int out_size, void* d_ws, size_t ws_size,
                              hipStream_t stream) {
    const float* logits  = (const float*)d_in[0];
    const float* pboxes  = (const float*)d_in[1];
    const float* gboxes  = (const float*)d_in[2];
    const int*   glabels = (const int*)d_in[3];

    float* out = (float*)d_out;
    const size_t BQG = (size_t)B_ * Q_ * G_;
    float* out_match = out;
    float* out_cost  = out + BQG;
    float* out_iou   = out + 2 * BQG;

    // workspace layout (~33 MB)
    char* ws = (char*)d_ws;
    size_t off = 0;
    u64*   pcost  = (u64*)  (ws + off); off += (size_t)B_ * NCH * G_ * 5 * 8;
    float* piou   = (float*)(ws + off); off += (size_t)B_ * NCH * G_ * 5 * 4;
    u64*   cand   = (u64*)  (ws + off); off += (size_t)B_ * G_ * 5 * 8;
    int*   ramin  = (int*)  (ws + off); off += (size_t)B_ * Q_ * 4;
    int*   cnt    = (int*)  (ws + off); off += (size_t)B_ * Q_ * 4;
    int*   gsel   = (int*)  (ws + off); off += (size_t)B_ * Q_ * 4;
    int*   rmf    = (int*)  (ws + off); off += (size_t)B_ * Q_ * 4;

    fused_cost_kernel<<<dim3(NCH, B_), 256, 0, stream>>>(
        logits, pboxes, gboxes, glabels, out_cost, out_iou, piou, pcost, ramin, cnt);
    dynk_scatter_kernel<<<B_ * G_, 256, 0, stream>>>(pcost, piou, cand, cnt, gsel);
    loop_kernel<<<B_, 64, 0, stream>>>(out_cost, cnt, gsel, ramin, cand, rmf);
    expand_kernel<<<(int)(BQG / 4 / 256), 256, 0, stream>>>(rmf, out_match);
}

// Round 3
// 214.019 us; speedup vs baseline: 1.1903x; 1.1903x over previous
//
#include <hip/hip_runtime.h>
#include <cstdint>
#include <cstddef>

#define B_ 16
#define Q_ 4096
#define G_ 128
#define C_ 80
#define QCHUNK 16
#define QBLK 64                 // q's per A-block (4 chunks)
#define CHPB (QBLK / QCHUNK)    // 4 chunks per block
#define NCH2 (Q_ / QBLK)        // 64 partial lists per column

typedef unsigned long long u64;
#define U64MAX 0xffffffffffffffffull

// pack (cost,q) into a sortable u64 key: asc key order == lex (cost asc, q asc)
__device__ __forceinline__ u64 packkey(float v, int q) {
    unsigned int bts = __float_as_uint(v);
    if (bts == 0x80000000u) bts = 0u;  // -0.0 -> +0.0
    bts = (bts & 0x80000000u) ? ~bts : (bts | 0x80000000u);
    return ((u64)bts << 32) | (unsigned int)q;
}

__device__ __forceinline__ u64 umin64(u64 a, u64 b) { return a < b ? a : b; }
__device__ __forceinline__ u64 umax64(u64 a, u64 b) { return a > b ? a : b; }

// merge two desc-sorted 5-lists -> top-5 desc (branchless network)
__device__ __forceinline__ void merge5_desc(
    float& a0, float& a1, float& a2, float& a3, float& a4,
    float b0, float b1, float b2, float b3, float b4)
{
    const float r0 = fmaxf(a0, b0);
    const float r1 = fmaxf(fmaxf(a1, b1), fminf(a0, b0));
    const float r2 = fmaxf(fmaxf(a2, b2), fmaxf(fminf(a0, b1), fminf(a1, b0)));
    const float r3 = fmaxf(fmaxf(a3, b3),
                     fmaxf(fminf(a0, b2), fmaxf(fminf(a1, b1), fminf(a2, b0))));
    const float r4 = fmaxf(fmaxf(a4, b4),
                     fmaxf(fmaxf(fminf(a0, b3), fminf(a3, b0)),
                           fmaxf(fminf(a1, b2), fminf(a2, b1))));
    a0 = r0; a1 = r1; a2 = r2; a3 = r3; a4 = r4;
}

// merge two asc-sorted 5-lists of u64 keys -> bottom-5 asc
__device__ __forceinline__ void merge5_asc(
    u64& a0, u64& a1, u64& a2, u64& a3, u64& a4,
    u64 b0, u64 b1, u64 b2, u64 b3, u64 b4)
{
    const u64 r0 = umin64(a0, b0);
    const u64 r1 = umin64(umin64(a1, b1), umax64(a0, b0));
    const u64 r2 = umin64(umin64(a2, b2), umin64(umax64(a0, b1), umax64(a1, b0)));
    const u64 r3 = umin64(umin64(a3, b3),
                   umin64(umax64(a0, b2), umin64(umax64(a1, b1), umax64(a2, b0))));
    const u64 r4 = umin64(umin64(a4, b4),
                   umin64(umin64(umax64(a0, b3), umax64(a3, b0)),
                          umin64(umax64(a1, b2), umax64(a2, b1))));
    a0 = r0; a1 = r1; a2 = r2; a3 = r3; a4 = r4;
}

__device__ __forceinline__ float focal_cost(float x) {
    float p;
    if (x >= 0.f) { const float e = expf(-x); p = 1.f / (1.f + e); }
    else          { const float e = expf(x);  p = e / (1.f + e); }
    const float pos = 0.25f * (1.f - p) * (1.f - p) * (-logf(p + 1e-8f));
    const float neg = 0.75f * p * p * (-logf(1.f - p + 1e-8f));
    return pos - neg;
}

// stable conditional-swap insertion level for (cost,q) lex order (strict <)
__device__ __forceinline__ void ins_level(float& c, int& j, float& x, int& qx) {
    const bool s  = x < c;
    const float nc = s ? x : c;
    const float nx = s ? c : x;
    const int   nj = s ? qx : j;
    const int   nq = s ? j : qx;
    c = nc; x = nx; j = nj; qx = nq;
}

// ---------------------------------------------------------------------------
// Kernel A: fused cost/iou + focal.  Each block now covers 64 q's (4 chunks
// of 16), amortizing the gt-constant preamble 4x and shrinking the partial
// lists to 64 per column.  Selection state (bottom-5 cost keys w/ GLOBAL q,
// top-5 iou) runs in registers across chunks; chunks are processed in
// ascending-q order so stable strict-< insertion preserves the exact
// (cost asc, q asc) lex tie-break.  Row-argmin per chunk as before.
// ---------------------------------------------------------------------------
__global__ __launch_bounds__(256) void fused_cost_kernel(
    const float* __restrict__ logits,
    const float* __restrict__ pboxes,
    const float* __restrict__ gboxes,
    const int*   __restrict__ glabels,
    float* __restrict__ out_cost,
    float* __restrict__ out_iou,
    float* __restrict__ piou,
    u64*   __restrict__ pcost,
    int*   __restrict__ ramin)
{
    const int tid = threadIdx.x;
    const int g   = tid & 127;
    const int qh  = tid >> 7;
    const int ci  = blockIdx.x, b = blockIdx.y;

    __shared__ float pq[QCHUNK][16];
    __shared__ int   fgf[QCHUNK];
    __shared__ float lbuf[QCHUNK * 80];          // focal class-cost table
    __shared__ float2 citile[QCHUNK][G_ + 2];    // (cost, iou) per pair

    // ---- per-thread gt constants (loaded once for all 4 chunks) ----
    const float4* gb4 = (const float4*)(gboxes + ((size_t)b * G_ + g) * 8);
    const float4 gA = gb4[0], gB = gb4[1];
    const float g0 = gA.x, g1 = gA.y, g2 = gA.z, g3 = gA.w;
    const float g4 = gB.x, g5 = gB.y, g6 = gB.z, g7 = gB.w;
    const float gxc = (g0 + g2 + g4 + g6) * 0.25f;
    const float gyc = (g1 + g3 + g5 + g7) * 0.25f;
    const float gw = sqrtf((g0 - g2) * (g0 - g2) + (g1 - g3) * (g1 - g3));
    const float gh = sqrtf((g2 - g4) * (g2 - g4) + (g3 - g5) * (g3 - g5));
    const float gax0 = gxc - gw * 0.5f, gay0 = gyc - gh * 0.5f;
    const float gax1 = gxc + gw * 0.5f, gay1 = gyc + gh * 0.5f;
    const float garea = (gax1 - gax0) * (gay1 - gay0);
    const float v1x = g2 - g0, v1y = g3 - g1, v2x = g4 - g0, v2y = g5 - g1;
    const float gt_area = fabsf(v1x * v2y - v1y * v2x) * 0.5f;
    const float mxx = fmaxf(fmaxf(g0, g2), fmaxf(g4, g6));
    const float mnx = fminf(fminf(g0, g2), fminf(g4, g6));
    const float mxy = fmaxf(fmaxf(g1, g3), fmaxf(g5, g7));
    const float mny = fminf(fminf(g1, g3), fminf(g5, g7));
    const float dgx = mxx - mnx, dgy = mxy - mny;
    const float radius = sqrtf(dgx * dgx + dgy * dgy) / 32.0f;
    const float thresh = gt_area / radius;
    const int lab = glabels[b * G_ + g];

    // running selection state (used by tid<128 threads only)
    float c0 = 1e38f, c1 = 1e38f, c2 = 1e38f, c3 = 1e38f, c4 = 1e38f;
    int   j0 = 0, j1 = 0, j2 = 0, j3 = 0, j4 = 0;
    float t0 = 0.f, t1 = 0.f, t2 = 0.f, t3 = 0.f, t4 = 0.f;

    #pragma unroll 1
    for (int ch = 0; ch < CHPB; ++ch) {
        const int q0 = ci * QBLK + ch * QCHUNK;

        // ---- stage pred boxes (16 q x 8 floats = 32 float4) ----
        if (tid < 32) {
            const float4 v = ((const float4*)(pboxes + ((size_t)b * Q_ + q0) * 8))[tid];
            *(float4*)&pq[tid >> 1][(tid & 1) * 4] = v;
        }
        __syncthreads();
        if (tid < QCHUNK) {
            const float* pr = pq[tid];
            const float p0 = pr[0], p1 = pr[1], p2 = pr[2], p3 = pr[3];
            const float p4 = pr[4], p5v = pr[5], p6 = pr[6], p7 = pr[7];
            const float pxc = (p0 + p2 + p4 + p6) * 0.25f;
            const float pyc = (p1 + p3 + p5v + p7) * 0.25f;
            const float pw = sqrtf((p0 - p2) * (p0 - p2) + (p1 - p3) * (p1 - p3));
            const float ph = sqrtf((p2 - p4) * (p2 - p4) + (p3 - p5v) * (p3 - p5v));
            pq[tid][8]  = pxc;
            pq[tid][9]  = pyc;
            pq[tid][10] = pxc - pw * 0.5f;
            pq[tid][11] = pyc - ph * 0.5f;
            pq[tid][12] = pxc + pw * 0.5f;
            pq[tid][13] = pyc + ph * 0.5f;
            pq[tid][14] = pw * ph;
            fgf[tid] = 0;
        }
        __syncthreads();
        // focal class-cost table for this chunk (16 q x 80 classes)
        for (int j = tid; j < QCHUNK * 80; j += 256)
            lbuf[j] = focal_cost(logits[((size_t)b * Q_ + q0) * 80 + j]);

        // ---- fg mask (any over g); fgf written by lane0 of each wave ----
        const int lane0 = ((tid & 63) == 0);
        for (int i = 0; i < QCHUNK / 2; ++i) {
            const int ql = 2 * i + qh;
            const float dx = pq[ql][8] - gxc, dy = pq[ql][9] - gyc;
            const int in = sqrtf(dx * dx + dy * dy) <= thresh;
            const int anyin = __any(in);
            if (anyin && lane0) fgf[ql] = 1;
        }
        __syncthreads();

        // ---- main loop: full cost + (cost,iou) tile write ----
        #pragma unroll
        for (int jj = 0; jj < 8; ++jj) {
            const int qls = 2 * jj + qh;       // 0..15
            const int q   = q0 + qls;
            const float4 prA = *(const float4*)&pq[qls][0];
            const float4 prB = *(const float4*)&pq[qls][4];
            const float4 prC = *(const float4*)&pq[qls][8];
            const float4 prD = *(const float4*)&pq[qls][12];
            const float p0 = prA.x, p1 = prA.y, p2 = prA.z, p3 = prA.w;
            const float p4 = prB.x, p5v = prB.y, p6 = prB.z, p7 = prB.w;
            const float pxc = prC.x, pyc = prC.y;
            const float pax0 = prC.z, pay0 = prC.w, pax1 = prD.x, pay1 = prD.y;
            const float parea = prD.z;

            const float l1 = fabsf(p0 - g0) + fabsf(p1 - g1) + fabsf(p2 - g2)
                           + fabsf(p3 - g3) + fabsf(p4 - g4) + fabsf(p5v - g5)
                           + fabsf(p6 - g6) + fabsf(p7 - g7);

            const float ltx = fmaxf(pax0, gax0), lty = fmaxf(pay0, gay0);
            const float rbx = fminf(pax1, gax1), rby = fminf(pay1, gay1);
            const float iw = fmaxf(rbx - ltx, 0.f), ih = fmaxf(rby - lty, 0.f);
            const float inter = iw * ih;
            const float iou = inter / (parea + garea - inter + 1e-8f);

            const float ew = fmaxf(pax1, gax1) - fminf(pax0, gax0);
            const float eh = fmaxf(pay1, gay1) - fminf(pay0, gay0);
            const float cc2 = ew * ew + eh * eh + 1e-8f;
            const float dx = pxc - gxc, dy = pyc - gyc;
            const float diou = iou - (dx * dx + dy * dy) / cc2;

            const float cclass = lbuf[qls * 80 + lab];
            const float cost = 5.f * l1 + 2.f * cclass + 2.f * diou
                             + (fgf[qls] ? 0.f : 10000.f);

            const size_t o = ((size_t)b * Q_ + q) * G_ + g;
            out_cost[o] = cost;
            out_iou[o]  = iou;
            citile[qls][g] = make_float2(cost, iou);
        }
        __syncthreads();   // citile complete

        if (tid < G_) {
            // running per-column selection; insert GLOBAL q
            #pragma unroll
            for (int qq = 0; qq < QCHUNK; ++qq) {
                const float2 cv = citile[qq][tid];
                float x = cv.x; int qx = q0 + qq;
                ins_level(c0, j0, x, qx);
                ins_level(c1, j1, x, qx);
                ins_level(c2, j2, x, qx);
                ins_level(c3, j3, x, qx);
                ins_level(c4, j4, x, qx);
                float y = cv.y, m;
                m = fmaxf(t0, y); y = fminf(t0, y); t0 = m;
                m = fmaxf(t1, y); y = fminf(t1, y); t1 = m;
                m = fmaxf(t2, y); y = fminf(t2, y); t2 = m;
                m = fmaxf(t3, y); y = fminf(t3, y); t3 = m;
                t4 = fmaxf(t4, y);
            }
        } else {
            // ---- row argmin (first-index tie-break), 8 lanes per q ----
            const int t    = tid - 128;
            const int part = t & 7;        // 0..7
            const int row  = t >> 3;       // 0..15
            float v = 1e38f; int mg = 0x7fffffff;
            #pragma unroll
            for (int j = 0; j < 16; ++j) {
                const int gg = part + 8 * j;           // ascending per lane
                const float c = citile[row][gg].x;
                if (c < v) { v = c; mg = gg; }         // strict <: first index
            }
            #pragma unroll
            for (int off = 1; off < 8; off <<= 1) {
                const float ov = __shfl_xor(v, off);
                const int   og = __shfl_xor(mg, off);
                if (ov < v || (ov == v && og < mg)) { v = ov; mg = og; }
            }
            if (part == 0) ramin[b * Q_ + q0 + row] = mg;
        }
        // next chunk's first __syncthreads() guards citile reuse
    }

    if (tid < G_) {
        // coalesced layout: [B][NCH2][G][5]
        const size_t pbase = (((size_t)b * NCH2 + ci) * G_ + tid) * 5;
        piou[pbase + 0] = t0; piou[pbase + 1] = t1; piou[pbase + 2] = t2;
        piou[pbase + 3] = t3; piou[pbase + 4] = t4;
        pcost[pbase + 0] = packkey(c0, j0);
        pcost[pbase + 1] = packkey(c1, j1);
        pcost[pbase + 2] = packkey(c2, j2);
        pcost[pbase + 3] = packkey(c3, j3);
        pcost[pbase + 4] = packkey(c4, j4);
    }
}

// ---------------------------------------------------------------------------
// Kernel C: per-batch refinement, 1024 threads (16 waves) — the verified
// round-1 structure — with former kernel B folded into the prologue: each
// wave butterfly-merges the 64 partial lists for 8 columns (exact hypercube
// allreduce over one wave), computes dyn_k, and scatters cnt/gsel into LDS
// (newh doubles as the cnt accumulator during init; re-zeroed after).
// ---------------------------------------------------------------------------
__global__ __launch_bounds__(1024) void loop_kernel(
    const float* __restrict__ cost,
    const u64*   __restrict__ pcost,
    const float* __restrict__ piou,
    const int*   __restrict__ ramin,
    int* __restrict__ rmatch_final)
{
    const int b = blockIdx.x, tid = threadIdx.x;
    const int wv = tid >> 6, ln = tid & 63;

    __shared__ short rmatch[Q_];            // 8 KB
    __shared__ unsigned char s_ra[Q_];      // 4 KB
    __shared__ int  newh[Q_];               // 16 KB (cnt during init)
    __shared__ unsigned char newg[Q_];      // 4 KB
    __shared__ short s_gsel[Q_];            // 8 KB
    __shared__ u64 scand[G_][5];            // 5 KB
    __shared__ int ptrs[G_], col_cnt[G_], unm_list[G_], prop[G_], fb_slot[G_], touched[G_];
    __shared__ int n_unm, n_fb, n_touch;

    for (int q = tid; q < Q_; q += 1024) newh[q] = 0;
    __syncthreads();

    // ---- merged dynk+scatter (was kernel B): wave wv handles cols wv*8+k ----
    for (int k = 0; k < 8; ++k) {
        const int g = wv * 8 + k;
        const size_t base = (((size_t)b * NCH2 + ln) * G_ + g) * 5;
        u64 k0 = pcost[base + 0], k1 = pcost[base + 1], k2 = pcost[base + 2],
            k3 = pcost[base + 3], k4 = pcost[base + 4];
        float s0 = piou[base + 0], s1 = piou[base + 1], s2 = piou[base + 2],
              s3 = piou[base + 3], s4 = piou[base + 4];
        #pragma unroll
        for (int off = 1; off < 64; off <<= 1) {
            merge5_asc(k0, k1, k2, k3, k4,
                       __shfl_xor(k0, off), __shfl_xor(k1, off), __shfl_xor(k2, off),
                       __shfl_xor(k3, off), __shfl_xor(k4, off));
            merge5_desc(s0, s1, s2, s3, s4,
                        __shfl_xor(s0, off), __shfl_xor(s1, off), __shfl_xor(s2, off),
                        __shfl_xor(s3, off), __shfl_xor(s4, off));
        }
        if (ln == 0) {
            scand[g][0] = k0; scand[g][1] = k1; scand[g][2] = k2;
            scand[g][3] = k3; scand[g][4] = k4;
            ptrs[g] = 0;
            const float s = s0 + s1 + s2 + s3 + s4;
            int dynk = (int)s;
            if (dynk < 1) dynk = 1;
            if (dynk > 5) dynk = 5;
            const u64 ks[5] = {k0, k1, k2, k3, k4};
            #pragma unroll
            for (int i = 0; i < 5; ++i) {
                if (i < dynk) {
                    const int q = (int)(ks[i] & 0xffffffffu);
                    atomicAdd(&newh[q], 1);
                    s_gsel[q] = (short)g;   // only read when cnt==1
                }
            }
        }
    }
    __syncthreads();

    // ---- rmatch init from LDS cnt/gsel + global ramin; re-zero newh ----
    for (int q = tid; q < Q_; q += 1024) {
        const int c  = newh[q];
        const int ra = ramin[b * Q_ + q];
        s_ra[q] = (unsigned char)ra;
        rmatch[q] = (c == 0) ? (short)-1
                             : (c == 1 ? s_gsel[q] : (short)ra);
        newh[q] = 0;
    }
    if (tid < G_) col_cnt[tid] = 0;
    __syncthreads();
    for (int q = tid; q < Q_; q += 1024)
        if (rmatch[q] >= 0) atomicAdd(&col_cnt[rmatch[q]], 1);
    __syncthreads();

    const float* costb = cost + (size_t)b * Q_ * G_;

    for (int it = 0; it < G_; ++it) {
        if (tid == 0) { n_unm = 0; n_fb = 0; n_touch = 0; }
        __syncthreads();
        if (tid < G_ && col_cnt[tid] == 0)
            unm_list[atomicAdd(&n_unm, 1)] = tid;
        __syncthreads();
        const int nu = n_unm;
        if (nu == 0) break;

        // propose: first unmatched candidate, else mark for fallback scan
        if (tid < nu) {
            const int g = unm_list[tid];
            int p = ptrs[g];
            int q = -1;
            while (p < 5) {
                const int cq = (int)(scand[g][p] & 0xffffffffu);
                if (rmatch[cq] < 0) { q = cq; break; }
                ++p;
            }
            ptrs[g] = p;
            prop[tid] = q;
            if (q < 0) fb_slot[atomicAdd(&n_fb, 1)] = tid;
        }
        __syncthreads();

        // wave-parallel fallback (16 waves): bottom-5 unmatched + refill.
        const int nf = n_fb;
        for (int i = wv; i < nf; i += 16) {
            const int slot = fb_slot[i];
            const int g = unm_list[slot];
            const float* colp = costb + g;
            u64 k0 = U64MAX, k1 = U64MAX, k2 = U64MAX, k3 = U64MAX, k4 = U64MAX;
            for (int q = ln; q < Q_; q += 64) {
                if (rmatch[q] < 0) {
                    const float v = colp[(size_t)q * G_];
                    const u64 kk = packkey(v, q);
                    if (kk < k4) {
                        if (kk < k0)      { k4 = k3; k3 = k2; k2 = k1; k1 = k0; k0 = kk; }
                        else if (kk < k1) { k4 = k3; k3 = k2; k2 = k1; k1 = kk; }
                        else if (kk < k2) { k4 = k3; k3 = k2; k2 = kk; }
                        else if (kk < k3) { k4 = k3; k3 = kk; }
                        else              { k4 = kk; }
                    }
                }
            }
            #pragma unroll
            for (int off = 1; off < 64; off <<= 1) {
                merge5_asc(k0, k1, k2, k3, k4,
                           __shfl_xor(k0, off), __shfl_xor(k1, off), __shfl_xor(k2, off),
                           __shfl_xor(k3, off), __shfl_xor(k4, off));
            }
            if (ln == 0) {
                scand[g][0] = k0; scand[g][1] = k1; scand[g][2] = k2;
                scand[g][3] = k3; scand[g][4] = k4;
                ptrs[g] = 0;
                prop[slot] = (int)(k0 & 0xffffffffu);
            }
        }
        __syncthreads();

        // hits
        if (tid < nu) {
            const int q = prop[tid];
            newg[q] = (unsigned char)unm_list[tid];  // consumed only when nh==1
            if (atomicAdd(&newh[q], 1) == 0)
                touched[atomicAdd(&n_touch, 1)] = q;
        }
        __syncthreads();

        // resolve (dedup): hits only land on unmatched rows
        const int nt = n_touch;
        if (tid < nt) {
            const int q = touched[tid];
            const int nh = newh[q];
            const int gg = (nh == 1) ? (int)newg[q] : (int)s_ra[q];
            rmatch[q] = (short)gg;
            atomicAdd(&col_cnt[gg], 1);
            newh[q] = 0;
        }
        __syncthreads();
    }

    for (int q = tid; q < Q_; q += 1024)
        rmatch_final[b * Q_ + q] = rmatch[q];
}

// ---------------------------------------------------------------------------
// Kernel D: expand rmatch -> full match plane (fully parallel float4 writes).
// ---------------------------------------------------------------------------
__global__ __launch_bounds__(256) void expand_kernel(
    const int* __restrict__ rmatch_final, float* __restrict__ out_match)
{
    const int idx = blockIdx.x * 256 + threadIdx.x;  // float4 index
    const int row = idx >> 5;                        // G/4 = 32 float4 per row
    const int gb  = (idx & 31) << 2;
    const int rm  = rmatch_final[row];
    float4 o;
    o.x = (rm == gb)     ? 1.f : 0.f;
    o.y = (rm == gb + 1) ? 1.f : 0.f;
    o.z = (rm == gb + 2) ? 1.f : 0.f;
    o.w = (rm == gb + 3) ? 1.f : 0.f;
    ((float4*)out_match)[idx] = o;
}

extern "C" void kernel_launch(void* const* d_in, const int* in_sizes, int n_in,
                              void* d_out, int out_size, void* d_ws, size_t ws_size,
                              hipStream_t stream) {
    const float* logits  = (const float*)d_in[0];
    const float* pboxes  = (const float*)d_in[1];
    const float* gboxes  = (const float*)d_in[2];
    const int*   glabels = (const int*)d_in[3];

    float* out = (float*)d_out;
    const size_t BQG = (size_t)B_ * Q_ * G_;
    float* out_match = out;
    float* out_cost  = out + BQG;
    float* out_iou   = out + 2 * BQG;

    // workspace layout (~4.5 MB)
    char* ws = (char*)d_ws;
    size_t off = 0;
    u64*   pcost  = (u64*)  (ws + off); off += (size_t)B_ * NCH2 * G_ * 5 * 8;
    float* piou   = (float*)(ws + off); off += (size_t)B_ * NCH2 * G_ * 5 * 4;
    int*   ramin  = (int*)  (ws + off); off += (size_t)B_ * Q_ * 4;
    int*   rmf    = (int*)  (ws + off); off += (size_t)B_ * Q_ * 4;

    fused_cost_kernel<<<dim3(NCH2, B_), 256, 0, stream>>>(
        logits, pboxes, gboxes, glabels, out_cost, out_iou, piou, pcost, ramin);
    loop_kernel<<<B_, 1024, 0, stream>>>(out_cost, pcost, piou, ramin, rmf);
    expand_kernel<<<(int)(BQG / 4 / 256), 256, 0, stream>>>(rmf, out_match);
}

// Round 4
// 188.527 us; speedup vs baseline: 1.3513x; 1.1352x over previous
//
#include <hip/hip_runtime.h>
#include <cstdint>
#include <cstddef>

#define B_ 16
#define Q_ 4096
#define G_ 128
#define C_ 80
#define QCHUNK 16
#define QBLK 32                 // q's per A-block (2 chunks)
#define CHPB (QBLK / QCHUNK)    // 2 chunks per block
#define NCH (Q_ / QBLK)         // 128 partial lists per column

typedef unsigned long long u64;
#define U64MAX 0xffffffffffffffffull

// pack (cost,q) into a sortable u64 key: asc key order == lex (cost asc, q asc)
__device__ __forceinline__ u64 packkey(float v, int q) {
    unsigned int bts = __float_as_uint(v);
    if (bts == 0x80000000u) bts = 0u;  // -0.0 -> +0.0
    bts = (bts & 0x80000000u) ? ~bts : (bts | 0x80000000u);
    return ((u64)bts << 32) | (unsigned int)q;
}

__device__ __forceinline__ u64 umin64(u64 a, u64 b) { return a < b ? a : b; }
__device__ __forceinline__ u64 umax64(u64 a, u64 b) { return a > b ? a : b; }

// merge two desc-sorted 5-lists -> top-5 desc (branchless network)
__device__ __forceinline__ void merge5_desc(
    float& a0, float& a1, float& a2, float& a3, float& a4,
    float b0, float b1, float b2, float b3, float b4)
{
    const float r0 = fmaxf(a0, b0);
    const float r1 = fmaxf(fmaxf(a1, b1), fminf(a0, b0));
    const float r2 = fmaxf(fmaxf(a2, b2), fmaxf(fminf(a0, b1), fminf(a1, b0)));
    const float r3 = fmaxf(fmaxf(a3, b3),
                     fmaxf(fminf(a0, b2), fmaxf(fminf(a1, b1), fminf(a2, b0))));
    const float r4 = fmaxf(fmaxf(a4, b4),
                     fmaxf(fmaxf(fminf(a0, b3), fminf(a3, b0)),
                           fmaxf(fminf(a1, b2), fminf(a2, b1))));
    a0 = r0; a1 = r1; a2 = r2; a3 = r3; a4 = r4;
}

// merge two asc-sorted 5-lists of u64 keys -> bottom-5 asc
__device__ __forceinline__ void merge5_asc(
    u64& a0, u64& a1, u64& a2, u64& a3, u64& a4,
    u64 b0, u64 b1, u64 b2, u64 b3, u64 b4)
{
    const u64 r0 = umin64(a0, b0);
    const u64 r1 = umin64(umin64(a1, b1), umax64(a0, b0));
    const u64 r2 = umin64(umin64(a2, b2), umin64(umax64(a0, b1), umax64(a1, b0)));
    const u64 r3 = umin64(umin64(a3, b3),
                   umin64(umax64(a0, b2), umin64(umax64(a1, b1), umax64(a2, b0))));
    const u64 r4 = umin64(umin64(a4, b4),
                   umin64(umin64(umax64(a0, b3), umax64(a3, b0)),
                          umin64(umax64(a1, b2), umax64(a2, b1))));
    a0 = r0; a1 = r1; a2 = r2; a3 = r3; a4 = r4;
}

__device__ __forceinline__ float focal_cost(float x) {
    float p;
    if (x >= 0.f) { const float e = expf(-x); p = 1.f / (1.f + e); }
    else          { const float e = expf(x);  p = e / (1.f + e); }
    const float pos = 0.25f * (1.f - p) * (1.f - p) * (-logf(p + 1e-8f));
    const float neg = 0.75f * p * p * (-logf(1.f - p + 1e-8f));
    return pos - neg;
}

// stable conditional-swap insertion level for (cost,q) lex order (strict <)
__device__ __forceinline__ void ins_level(float& c, int& j, float& x, int& qx) {
    const bool s  = x < c;
    const float nc = s ? x : c;
    const float nx = s ? c : x;
    const int   nj = s ? qx : j;
    const int   nq = s ? j : qx;
    c = nc; x = nx; j = nj; qx = nq;
}

// ---------------------------------------------------------------------------
// Kernel A: fused cost/iou + focal.  2 chunks per block (QBLK=32): grid 2048
// blocks = 8/CU issued (LDS-resident 6 -> occupancy back to ~75%, vs round-3's
// grid-limited 30%).  Tiles split into two padded FLOAT arrays (b32, stride-1
// column reads are 2-way = free; round-3's float2 b64 pattern was 1.24M
// conflicts).  32-bit incremental addressing for output-plane stores.
// Selection state (bottom-5 cost keys w/ global q, top-5 iou) in registers
// across chunks; ascending-q insertion preserves exact lex tie-break.
// Also zeroes cnt for its 32 q's.
// ---------------------------------------------------------------------------
__global__ __launch_bounds__(256) void fused_cost_kernel(
    const float* __restrict__ logits,
    const float* __restrict__ pboxes,
    const float* __restrict__ gboxes,
    const int*   __restrict__ glabels,
    float* __restrict__ out_cost,
    float* __restrict__ out_iou,
    float* __restrict__ piou,
    u64*   __restrict__ pcost,
    int*   __restrict__ ramin,
    int*   __restrict__ cnt)
{
    const int tid = threadIdx.x;
    const int g   = tid & 127;
    const int qh  = tid >> 7;
    const int ci  = blockIdx.x, b = blockIdx.y;

    __shared__ float pq[QCHUNK][16];
    __shared__ int   fgf[QCHUNK];
    __shared__ float lbuf[QCHUNK * 80];          // focal class-cost table
    __shared__ float s_cost[QCHUNK][G_ + 1];     // cost tile (b32, padded)
    __shared__ float s_iou[QCHUNK][G_ + 1];      // iou tile

    // zero cnt for this block's 32 q's (consumed by B's atomics)
    if (tid < QBLK) cnt[b * Q_ + ci * QBLK + tid] = 0;

    // ---- per-thread gt constants (loaded once for both chunks) ----
    const float4* gb4 = (const float4*)(gboxes + ((size_t)b * G_ + g) * 8);
    const float4 gA = gb4[0], gB = gb4[1];
    const float g0 = gA.x, g1 = gA.y, g2 = gA.z, g3 = gA.w;
    const float g4 = gB.x, g5 = gB.y, g6 = gB.z, g7 = gB.w;
    const float gxc = (g0 + g2 + g4 + g6) * 0.25f;
    const float gyc = (g1 + g3 + g5 + g7) * 0.25f;
    const float gw = sqrtf((g0 - g2) * (g0 - g2) + (g1 - g3) * (g1 - g3));
    const float gh = sqrtf((g2 - g4) * (g2 - g4) + (g3 - g5) * (g3 - g5));
    const float gax0 = gxc - gw * 0.5f, gay0 = gyc - gh * 0.5f;
    const float gax1 = gxc + gw * 0.5f, gay1 = gyc + gh * 0.5f;
    const float garea = (gax1 - gax0) * (gay1 - gay0);
    const float v1x = g2 - g0, v1y = g3 - g1, v2x = g4 - g0, v2y = g5 - g1;
    const float gt_area = fabsf(v1x * v2y - v1y * v2x) * 0.5f;
    const float mxx = fmaxf(fmaxf(g0, g2), fmaxf(g4, g6));
    const float mnx = fminf(fminf(g0, g2), fminf(g4, g6));
    const float mxy = fmaxf(fmaxf(g1, g3), fmaxf(g5, g7));
    const float mny = fminf(fminf(g1, g3), fminf(g5, g7));
    const float dgx = mxx - mnx, dgy = mxy - mny;
    const float radius = sqrtf(dgx * dgx + dgy * dgy) / 32.0f;
    const float thresh = gt_area / radius;
    const int lab = glabels[b * G_ + g];

    // running selection state (used by tid<128 threads only)
    float c0 = 1e38f, c1 = 1e38f, c2 = 1e38f, c3 = 1e38f, c4 = 1e38f;
    int   j0 = 0, j1 = 0, j2 = 0, j3 = 0, j4 = 0;
    float t0 = 0.f, t1 = 0.f, t2 = 0.f, t3 = 0.f, t4 = 0.f;

    for (int ch = 0; ch < CHPB; ++ch) {
        const int q0 = ci * QBLK + ch * QCHUNK;

        // ---- stage pred boxes (16 q x 8 floats = 32 float4) ----
        if (tid < 32) {
            const float4 v = ((const float4*)(pboxes + ((size_t)b * Q_ + q0) * 8))[tid];
            *(float4*)&pq[tid >> 1][(tid & 1) * 4] = v;
        }
        __syncthreads();
        if (tid < QCHUNK) {
            const float* pr = pq[tid];
            const float p0 = pr[0], p1 = pr[1], p2 = pr[2], p3 = pr[3];
            const float p4 = pr[4], p5v = pr[5], p6 = pr[6], p7 = pr[7];
            const float pxc = (p0 + p2 + p4 + p6) * 0.25f;
            const float pyc = (p1 + p3 + p5v + p7) * 0.25f;
            const float pw = sqrtf((p0 - p2) * (p0 - p2) + (p1 - p3) * (p1 - p3));
            const float ph = sqrtf((p2 - p4) * (p2 - p4) + (p3 - p5v) * (p3 - p5v));
            pq[tid][8]  = pxc;
            pq[tid][9]  = pyc;
            pq[tid][10] = pxc - pw * 0.5f;
            pq[tid][11] = pyc - ph * 0.5f;
            pq[tid][12] = pxc + pw * 0.5f;
            pq[tid][13] = pyc + ph * 0.5f;
            pq[tid][14] = pw * ph;
            fgf[tid] = 0;
        }
        __syncthreads();
        // focal class-cost table for this chunk (16 q x 80 classes)
        for (int j = tid; j < QCHUNK * 80; j += 256)
            lbuf[j] = focal_cost(logits[((size_t)b * Q_ + q0) * 80 + j]);

        // ---- fg mask (any over g); fgf written by lane0 of each wave ----
        const int lane0 = ((tid & 63) == 0);
        for (int i = 0; i < QCHUNK / 2; ++i) {
            const int ql = 2 * i + qh;
            const float dx = pq[ql][8] - gxc, dy = pq[ql][9] - gyc;
            const int in = sqrtf(dx * dx + dy * dy) <= thresh;
            const int anyin = __any(in);
            if (anyin && lane0) fgf[ql] = 1;
        }
        __syncthreads();

        // ---- main loop: full cost + tile writes; 32-bit incremental addr ----
        int o = (b * Q_ + q0 + qh) * G_ + g;
        #pragma unroll
        for (int jj = 0; jj < 8; ++jj) {
            const int qls = 2 * jj + qh;       // 0..15
            const float4 prA = *(const float4*)&pq[qls][0];
            const float4 prB = *(const float4*)&pq[qls][4];
            const float4 prC = *(const float4*)&pq[qls][8];
            const float4 prD = *(const float4*)&pq[qls][12];
            const float p0 = prA.x, p1 = prA.y, p2 = prA.z, p3 = prA.w;
            const float p4 = prB.x, p5v = prB.y, p6 = prB.z, p7 = prB.w;
            const float pxc = prC.x, pyc = prC.y;
            const float pax0 = prC.z, pay0 = prC.w, pax1 = prD.x, pay1 = prD.y;
            const float parea = prD.z;

            const float l1 = fabsf(p0 - g0) + fabsf(p1 - g1) + fabsf(p2 - g2)
                           + fabsf(p3 - g3) + fabsf(p4 - g4) + fabsf(p5v - g5)
                           + fabsf(p6 - g6) + fabsf(p7 - g7);

            const float ltx = fmaxf(pax0, gax0), lty = fmaxf(pay0, gay0);
            const float rbx = fminf(pax1, gax1), rby = fminf(pay1, gay1);
            const float iw = fmaxf(rbx - ltx, 0.f), ih = fmaxf(rby - lty, 0.f);
            const float inter = iw * ih;
            const float iou = inter / (parea + garea - inter + 1e-8f);

            const float ew = fmaxf(pax1, gax1) - fminf(pax0, gax0);
            const float eh = fmaxf(pay1, gay1) - fminf(pay0, gay0);
            const float cc2 = ew * ew + eh * eh + 1e-8f;
            const float dx = pxc - gxc, dy = pyc - gyc;
            const float diou = iou - (dx * dx + dy * dy) / cc2;

            const float cclass = lbuf[qls * 80 + lab];
            const float cost = 5.f * l1 + 2.f * cclass + 2.f * diou
                             + (fgf[qls] ? 0.f : 10000.f);

            out_cost[o] = cost;
            out_iou[o]  = iou;
            o += 2 * G_;
            s_cost[qls][g] = cost;
            s_iou[qls][g]  = iou;
        }
        __syncthreads();   // tiles complete

        if (tid < G_) {
            // running per-column selection; insert GLOBAL q
            #pragma unroll
            for (int qq = 0; qq < QCHUNK; ++qq) {
                float x = s_cost[qq][tid]; int qx = q0 + qq;
                ins_level(c0, j0, x, qx);
                ins_level(c1, j1, x, qx);
                ins_level(c2, j2, x, qx);
                ins_level(c3, j3, x, qx);
                ins_level(c4, j4, x, qx);
                float y = s_iou[qq][tid], m;
                m = fmaxf(t0, y); y = fminf(t0, y); t0 = m;
                m = fmaxf(t1, y); y = fminf(t1, y); t1 = m;
                m = fmaxf(t2, y); y = fminf(t2, y); t2 = m;
                m = fmaxf(t3, y); y = fminf(t3, y); t3 = m;
                t4 = fmaxf(t4, y);
            }
        } else {
            // ---- row argmin (first-index tie-break), 8 lanes per q ----
            // each lane scans 16 consecutive g ascending; strict < keeps the
            // first index per lane; cross-lane tie-break takes min g.
            const int t    = tid - 128;
            const int part = t & 7;        // 0..7
            const int row  = t >> 3;       // 0..15
            float v = 1e38f; int mg = 0x7fffffff;
            #pragma unroll
            for (int j = 0; j < 16; ++j) {
                const int gg = part * 16 + j;          // ascending per lane
                const float c = s_cost[row][gg];
                if (c < v) { v = c; mg = gg; }         // strict <: first index
            }
            #pragma unroll
            for (int off = 1; off < 8; off <<= 1) {
                const float ov = __shfl_xor(v, off);
                const int   og = __shfl_xor(mg, off);
                if (ov < v || (ov == v && og < mg)) { v = ov; mg = og; }
            }
            if (part == 0) ramin[b * Q_ + q0 + row] = mg;
        }
        __syncthreads();   // tiles reusable next chunk
    }

    if (tid < G_) {
        // coalesced layout: [B][NCH][G][5]
        const size_t pbase = (((size_t)b * NCH + ci) * G_ + tid) * 5;
        piou[pbase + 0] = t0; piou[pbase + 1] = t1; piou[pbase + 2] = t2;
        piou[pbase + 3] = t3; piou[pbase + 4] = t4;
        pcost[pbase + 0] = packkey(c0, j0);
        pcost[pbase + 1] = packkey(c1, j1);
        pcost[pbase + 2] = packkey(c2, j2);
        pcost[pbase + 3] = packkey(c3, j3);
        pcost[pbase + 4] = packkey(c4, j4);
    }
}

// ---------------------------------------------------------------------------
// Kernel B: per-column (block = 128 threads = one thread per chunk-list):
// butterfly-merge 64 lists per wave, LDS-merge the 2 wave partials -> cand,
// dyn_k (same desc-sorted sum order as before), scatter cnt/gsel.
// 2048 blocks -> fully parallel across CUs (the round-3 in-C merge serialized
// on 16 CUs).
// ---------------------------------------------------------------------------
__global__ __launch_bounds__(128) void dynk_scatter_kernel(
    const u64*   __restrict__ pcost,
    const float* __restrict__ piou,
    u64* __restrict__ cand,
    int* __restrict__ cnt,
    int* __restrict__ gsel)
{
    const int col = blockIdx.x;          // b*G + g
    const int b = col >> 7, g = col & 127;
    const int tid = threadIdx.x;         // = chunk index ci (0..127)
    const int wv = tid >> 6, ln = tid & 63;

    __shared__ u64   wl[2][5];
    __shared__ float il[2][5];

    // layout [B][NCH][G][5]
    const size_t base = (((size_t)b * NCH + tid) * G_ + g) * 5;

    u64 k0 = pcost[base + 0], k1 = pcost[base + 1], k2 = pcost[base + 2],
        k3 = pcost[base + 3], k4 = pcost[base + 4];
    float t0 = piou[base + 0], t1 = piou[base + 1], t2 = piou[base + 2],
          t3 = piou[base + 3], t4 = piou[base + 4];

    #pragma unroll
    for (int off = 1; off < 64; off <<= 1) {
        merge5_asc(k0, k1, k2, k3, k4,
                   __shfl_xor(k0, off), __shfl_xor(k1, off), __shfl_xor(k2, off),
                   __shfl_xor(k3, off), __shfl_xor(k4, off));
        merge5_desc(t0, t1, t2, t3, t4,
                    __shfl_xor(t0, off), __shfl_xor(t1, off), __shfl_xor(t2, off),
                    __shfl_xor(t3, off), __shfl_xor(t4, off));
    }
    if (ln == 0) {
        wl[wv][0] = k0; wl[wv][1] = k1; wl[wv][2] = k2; wl[wv][3] = k3; wl[wv][4] = k4;
        il[wv][0] = t0; il[wv][1] = t1; il[wv][2] = t2; il[wv][3] = t3; il[wv][4] = t4;
    }
    __syncthreads();

    if (tid == 0) {
        u64 f0 = wl[0][0], f1 = wl[0][1], f2 = wl[0][2], f3 = wl[0][3], f4 = wl[0][4];
        merge5_asc(f0, f1, f2, f3, f4, wl[1][0], wl[1][1], wl[1][2], wl[1][3], wl[1][4]);
        float s0 = il[0][0], s1 = il[0][1], s2 = il[0][2], s3 = il[0][3], s4 = il[0][4];
        merge5_desc(s0, s1, s2, s3, s4, il[1][0], il[1][1], il[1][2], il[1][3], il[1][4]);

        cand[(size_t)col * 5 + 0] = f0;
        cand[(size_t)col * 5 + 1] = f1;
        cand[(size_t)col * 5 + 2] = f2;
        cand[(size_t)col * 5 + 3] = f3;
        cand[(size_t)col * 5 + 4] = f4;

        const float s = s0 + s1 + s2 + s3 + s4;
        int dynk = (int)s;
        if (dynk < 1) dynk = 1;
        if (dynk > 5) dynk = 5;
        const u64 ks[5] = {f0, f1, f2, f3, f4};
        #pragma unroll
        for (int i = 0; i < 5; ++i) {
            if (i < dynk) {
                const int q = (int)(ks[i] & 0xffffffffu);
                atomicAdd(&cnt[b * Q_ + q], 1);
                gsel[b * Q_ + q] = g;   // only read when cnt==1
            }
        }
    }
}

// ---------------------------------------------------------------------------
// Kernel C: per-batch event-driven refinement loop (1024 threads) — the
// verified round-1 structure.
// ---------------------------------------------------------------------------
__global__ __launch_bounds__(1024) void loop_kernel(
    const float* __restrict__ cost,
    const int* __restrict__ cnt,
    const int* __restrict__ gsel,
    const int* __restrict__ ramin,
    const u64* __restrict__ cand,
    int* __restrict__ rmatch_final)
{
    const int b = blockIdx.x, tid = threadIdx.x;
    const int wv = tid >> 6, ln = tid & 63;

    __shared__ short rmatch[Q_];            // 8 KB
    __shared__ unsigned char s_ra[Q_];      // 4 KB
    __shared__ int newh[Q_];                // 16 KB
    __shared__ unsigned char newg[Q_];      // 4 KB
    __shared__ u64 scand[G_][5];            // 5 KB
    __shared__ int ptrs[G_], col_cnt[G_], unm_list[G_], prop[G_], fb_slot[G_], touched[G_];
    __shared__ int n_unm, n_fb, n_touch;

    for (int q = tid; q < Q_; q += 1024) {
        const int c  = cnt[b * Q_ + q];
        const int ra = ramin[b * Q_ + q];
        s_ra[q] = (unsigned char)ra;
        newh[q] = 0;
        rmatch[q] = (c == 0) ? (short)-1
                             : (c == 1 ? (short)gsel[b * Q_ + q] : (short)ra);
    }
    if (tid < G_) { col_cnt[tid] = 0; ptrs[tid] = 0; }
    if (tid < G_ * 5)
        scand[tid / 5][tid % 5] = cand[(size_t)b * G_ * 5 + tid];
    __syncthreads();
    for (int q = tid; q < Q_; q += 1024)
        if (rmatch[q] >= 0) atomicAdd(&col_cnt[rmatch[q]], 1);
    __syncthreads();

    const float* costb = cost + (size_t)b * Q_ * G_;

    for (int it = 0; it < G_; ++it) {
        if (tid == 0) { n_unm = 0; n_fb = 0; n_touch = 0; }
        __syncthreads();
        if (tid < G_ && col_cnt[tid] == 0)
            unm_list[atomicAdd(&n_unm, 1)] = tid;
        __syncthreads();
        const int nu = n_unm;
        if (nu == 0) break;

        // propose: first unmatched candidate, else mark for fallback scan
        if (tid < nu) {
            const int g = unm_list[tid];
            int p = ptrs[g];
            int q = -1;
            while (p < 5) {
                const int cq = (int)(scand[g][p] & 0xffffffffu);
                if (rmatch[cq] < 0) { q = cq; break; }
                ++p;
            }
            ptrs[g] = p;
            prop[tid] = q;
            if (q < 0) fb_slot[atomicAdd(&n_fb, 1)] = tid;
        }
        __syncthreads();

        // wave-parallel fallback (16 waves): bottom-5 unmatched + refill.
        const int nf = n_fb;
        for (int i = wv; i < nf; i += 16) {
            const int slot = fb_slot[i];
            const int g = unm_list[slot];
            const float* colp = costb + g;
            u64 k0 = U64MAX, k1 = U64MAX, k2 = U64MAX, k3 = U64MAX, k4 = U64MAX;
            for (int q = ln; q < Q_; q += 64) {
                if (rmatch[q] < 0) {
                    const float v = colp[(size_t)q * G_];
                    const u64 kk = packkey(v, q);
                    if (kk < k4) {
                        if (kk < k0)      { k4 = k3; k3 = k2; k2 = k1; k1 = k0; k0 = kk; }
                        else if (kk < k1) { k4 = k3; k3 = k2; k2 = k1; k1 = kk; }
                        else if (kk < k2) { k4 = k3; k3 = k2; k2 = kk; }
                        else if (kk < k3) { k4 = k3; k3 = kk; }
                        else              { k4 = kk; }
                    }
                }
            }
            #pragma unroll
            for (int off = 1; off < 64; off <<= 1) {
                merge5_asc(k0, k1, k2, k3, k4,
                           __shfl_xor(k0, off), __shfl_xor(k1, off), __shfl_xor(k2, off),
                           __shfl_xor(k3, off), __shfl_xor(k4, off));
            }
            if (ln == 0) {
                scand[g][0] = k0; scand[g][1] = k1; scand[g][2] = k2;
                scand[g][3] = k3; scand[g][4] = k4;
                ptrs[g] = 0;
                prop[slot] = (int)(k0 & 0xffffffffu);
            }
        }
        __syncthreads();

        // hits
        if (tid < nu) {
            const int q = prop[tid];
            newg[q] = (unsigned char)unm_list[tid];  // consumed only when nh==1
            if (atomicAdd(&newh[q], 1) == 0)
                touched[atomicAdd(&n_touch, 1)] = q;
        }
        __syncthreads();

        // resolve (dedup): hits only land on unmatched rows
        const int nt = n_touch;
        if (tid < nt) {
            const int q = touched[tid];
            const int nh = newh[q];
            const int gg = (nh == 1) ? (int)newg[q] : (int)s_ra[q];
            rmatch[q] = (short)gg;
            atomicAdd(&col_cnt[gg], 1);
            newh[q] = 0;
        }
        __syncthreads();
    }

    for (int q = tid; q < Q_; q += 1024)
        rmatch_final[b * Q_ + q] = rmatch[q];
}

// ---------------------------------------------------------------------------
// Kernel D: expand rmatch -> full match plane (fully parallel float4 writes).
// ---------------------------------------------------------------------------
__global__ __launch_bounds__(256) void expand_kernel(
    const int* __restrict__ rmatch_final, float* __restrict__ out_match)
{
    const int idx = blockIdx.x * 256 + threadIdx.x;  // float4 index
    const int row = idx >> 5;                        // G/4 = 32 float4 per row
    const int gb  = (idx & 31) << 2;
    const int rm  = rmatch_final[row];
    float4 o;
    o.x = (rm == gb)     ? 1.f : 0.f;
    o.y = (rm == gb + 1) ? 1.f : 0.f;
    o.z = (rm == gb + 2) ? 1.f : 0.f;
    o.w = (rm == gb + 3) ? 1.f : 0.f;
    ((float4*)out_match)[idx] = o;
}

extern "C" void kernel_launch(void* const* d_in, const int* in_sizes, int n_in,
                              void* d_out, int out_size, void* d_ws, size_t ws_size,
                              hipStream_t stream) {
    const float* logits  = (const float*)d_in[0];
    const float* pboxes  = (const float*)d_in[1];
    const float* gboxes  = (const float*)d_in[2];
    const int*   glabels = (const int*)d_in[3];

    float* out = (float*)d_out;
    const size_t BQG = (size_t)B_ * Q_ * G_;
    float* out_match = out;
    float* out_cost  = out + BQG;
    float* out_iou   = out + 2 * BQG;

    // workspace layout (~9 MB)
    char* ws = (char*)d_ws;
    size_t off = 0;
    u64*   pcost  = (u64*)  (ws + off); off += (size_t)B_ * NCH * G_ * 5 * 8;
    float* piou   = (float*)(ws + off); off += (size_t)B_ * NCH * G_ * 5 * 4;
    u64*   cand   = (u64*)  (ws + off); off += (size_t)B_ * G_ * 5 * 8;
    int*   ramin  = (int*)  (ws + off); off += (size_t)B_ * Q_ * 4;
    int*   cnt    = (int*)  (ws + off); off += (size_t)B_ * Q_ * 4;
    int*   gsel   = (int*)  (ws + off); off += (size_t)B_ * Q_ * 4;
    int*   rmf    = (int*)  (ws + off); off += (size_t)B_ * Q_ * 4;

    fused_cost_kernel<<<dim3(NCH, B_), 256, 0, stream>>>(
        logits, pboxes, gboxes, glabels, out_cost, out_iou, piou, pcost, ramin, cnt);
    dynk_scatter_kernel<<<B_ * G_, 128, 0, stream>>>(pcost, piou, cand, cnt, gsel);
    loop_kernel<<<B_, 1024, 0, stream>>>(out_cost, cnt, gsel, ramin, cand, rmf);
    expand_kernel<<<(int)(BQG / 4 / 256), 256, 0, stream>>>(rmf, out_match);
}